// Round 14
// baseline (937.661 us; speedup 1.0000x reference)
//
#include <hip/hip_runtime.h>
#include <stdint.h>

#define BTOK 2048
#define HDIM 512
#define VOC  32000
#define BM 128
#define BN 128
#define BKM 64                   // K per step (MX 32x32x64)
#define NKTM (HDIM / BKM)        // 8 K-steps per vocab block
#define BLOBM (BM * BKM)         // 8192 B per (panel, kt) blob (fp8)
#define NVB (VOC / BN)           // 250
#define NRB (BTOK / BM)          // 16
#define NBLK (NVB * NRB)         // 4000 (fallback grid)
#define VBG 5                    // vocab blocks per strip
#define NVBG (NVB / VBG)         // 50
#define NSTRIP (NVBG * NRB)      // 800 (% 8 == 0)
#define NSLOT (NVBG * 2)         // 100 partial slots
#define NSTEP (VBG * NKTM)       // 40 global K-steps per block

// ws layout:
//   [0, 256)        blocksums
//   [65536, ..)     fp8 blobs: s_in | t_in | s_w | t_w
//   [PART_OFF, ..)  partials[5][NSLOT][BTOK] f32
#define WS_BLOB_OFF 65536
#define INB_B ((size_t)BTOK * HDIM)
#define WB_B  ((size_t)VOC * HDIM)
#define BLOB_BYTES (2 * INB_B + 2 * WB_B)          // 34,865,152
#define PART_OFF (WS_BLOB_OFF + BLOB_BYTES)
#define PART_BYTES ((size_t)5 * NSLOT * BTOK * 4)  // 4,096,000
#define WS_NEED (PART_OFF + PART_BYTES)            // ~39 MB

typedef __attribute__((ext_vector_type(8)))  short bf16x8;
typedef __attribute__((ext_vector_type(4)))  float f32x4;
typedef __attribute__((ext_vector_type(16))) float f32x16;
typedef __attribute__((ext_vector_type(8)))  int   i32x8;

__device__ __forceinline__ unsigned short f2b(float f) {
    union { float f; uint32_t u; } x; x.f = f;
    uint32_t u = x.u;
    u += 0x7fffu + ((u >> 16) & 1u);   // RNE (fallback path)
    return (unsigned short)(u >> 16);
}

// ---------------------------------------------------------------------------
// Pass 1: f32 -> fp8 e4m3 blobs. R14 piece-interleaved panel layout:
// byte (r, c) of a 128x64 panel at
//   e = (r>>5)*2048 + ((c&31)>>4)*1024 + ((c>>5)*32 + (r&31))*16 + (c&15)
// Consequence: lane l's 32B MFMA operand (row base+l&31, khalf=l>>5) is two
// 16B pieces at opBase + l*16 and opBase + 1024 + l*16 -> consecutive lanes
// at 16B stride = THE conflict-free ds_read_b128 pattern (R3 measured 0
// conflicts with exactly this stride; R12/R13's 32B-stride gave the constant
// 1.229e7 = 4-way). Same pattern = perfectly coalesced global loads for A.
// ---------------------------------------------------------------------------
__global__ __launch_bounds__(256) void convert_pack_mx(
    const float* __restrict__ s_in, const float* __restrict__ s_w,
    const float* __restrict__ t_in, const float* __restrict__ t_w,
    unsigned char* __restrict__ blob)
{
    unsigned char* sinb = blob;
    unsigned char* tinb = blob + INB_B;
    unsigned char* swb  = blob + 2 * INB_B;
    unsigned char* twb  = blob + 2 * INB_B + WB_B;
    const int total8 = (2 * BTOK + 2 * VOC) * (HDIM / 8);
    for (int f = blockIdx.x * 256 + threadIdx.x; f < total8; f += gridDim.x * 256) {
        const int row = f >> 6;
        const int c8i = f & 63;
        const float* src; unsigned char* dstb; int lrow;
        if (row < BTOK)                { src = s_in; dstb = sinb; lrow = row; }
        else if (row < BTOK + VOC)     { src = s_w;  dstb = swb;  lrow = row - BTOK; }
        else if (row < 2*BTOK + VOC)   { src = t_in; dstb = tinb; lrow = row - (BTOK + VOC); }
        else                           { src = t_w;  dstb = twb;  lrow = row - (2*BTOK + VOC); }
        const float* sp = src + (size_t)lrow * HDIM + c8i * 8;
        const float4 v0 = *reinterpret_cast<const float4*>(sp);
        const float4 v1 = *reinterpret_cast<const float4*>(sp + 4);
        const int p = lrow >> 7, r = lrow & 127;
        const int ccf = c8i * 8, kt = ccf >> 6, cc = ccf & 63;
        const int e = ((r >> 5) << 11) + (((cc & 31) >> 4) << 10)
                    + ((((cc >> 5) << 5) + (r & 31)) << 4) + (cc & 15);
        uint32_t w0 = 0, w1 = 0;
        w0 = __builtin_amdgcn_cvt_pk_fp8_f32(v0.x, v0.y, w0, false);
        w0 = __builtin_amdgcn_cvt_pk_fp8_f32(v0.z, v0.w, w0, true);
        w1 = __builtin_amdgcn_cvt_pk_fp8_f32(v1.x, v1.y, w1, false);
        w1 = __builtin_amdgcn_cvt_pk_fp8_f32(v1.z, v1.w, w1, true);
        uint2 pk; pk.x = w0; pk.y = w1;
        *reinterpret_cast<uint2*>(dstb + (size_t)(p * NKTM + kt) * BLOBM + e) = pk;
    }
}

__device__ __forceinline__ void gl_lds16(const unsigned char* g, unsigned char* l) {
    __builtin_amdgcn_global_load_lds(
        (__attribute__((address_space(1))) const void*)g,
        (__attribute__((address_space(3))) void*)l, 16, 0, 0);
}

__device__ __forceinline__ i32x8 mk8(const int4 lo, const int4 hi) {
    i32x8 v;
    v[0] = lo.x; v[1] = lo.y; v[2] = lo.z; v[3] = lo.w;
    v[4] = hi.x; v[5] = hi.y; v[6] = hi.z; v[7] = hi.w;
    return v;
}

// ---------------------------------------------------------------------------
// Strip GEMM (MX fp8 32x32x64, 8 waves, VBG=5). R14 structure:
//  - A operands in REGISTERS (per-lane 2x16B coalesced loads from L2-hot
//    blob, 1-step pipelined, static a/b parity names -> no scratch).
//  - B panels in LDS ring-3 (48 KB), staged 1-ahead via global_load_lds.
//  - ONE barrier per step. WAR audit: step s stages slot (s+1)%3, whose last
//    readers finished COMPUTE(s-1) before barrier(s), which the staging wave
//    already passed. vmcnt(6) = keep the 6 just-issued loads (4 A-reg +
//    2 B-DMA) in flight; only the final step drains to 0.
//  - All ds_reads conflict-free (16B lane stride, R14 blob layout).
// ---------------------------------------------------------------------------
__global__ __launch_bounds__(512, 2) void fused_gemm_mx(
    const unsigned char* __restrict__ blob,
    const int* __restrict__ labels, float* __restrict__ partials)
{
    __shared__ __align__(16) unsigned char smB[3][2][BLOBM];   // 48 KB ring
    __shared__ int lbl[BM];
    const unsigned char* sinb = blob;
    const unsigned char* tinb = blob + INB_B;
    const unsigned char* swb  = blob + 2 * INB_B;
    const unsigned char* twb  = blob + 2 * INB_B + WB_B;

    const int tid = threadIdx.x;
    const int orig = blockIdx.x;
    const int swzb = (orig & 7) * (NSTRIP / 8) + (orig >> 3);   // XCD-bijective
    const int vbg = swzb >> 4, rb = swzb & 15;
    const int row0 = rb * BM;
    if (tid < BM) lbl[tid] = labels[row0 + tid];
    __syncthreads();

    const int lane = tid & 63, wave = tid >> 6;
    const int wm = (wave >> 1) * 32;      // 4 M-strips of 32
    const int wn = (wave & 1) * 64;       // 2 N-strips of 64
    const int lrow = lane & 31, khalf = lane >> 5;

    // A-operand global offset: strip(wm>>5)*2048 + lane*16 (piece0; +1024 piece1)
    const int aoff = ((wave >> 1) << 11) + lane * 16;
    // B-operand LDS offsets within a panel
    const int bo0 = ((wave & 1) << 12) + lane * 16;   // fb0 piece0 (strip wn>>5)
    const int bo1 = bo0 + 2048;                       // fb1 piece0 (next strip)

    const unsigned char* aSrcS = sinb + (size_t)(rb * NKTM) * BLOBM + aoff;
    const unsigned char* aSrcT = tinb + (size_t)(rb * NKTM) * BLOBM + aoff;
    const unsigned char* bSrcS = swb + (size_t)(vbg * VBG * NKTM) * BLOBM;
    const unsigned char* bSrcT = twb + (size_t)(vbg * VBG * NKTM) * BLOBM;

    // strip-accumulated loss partials (statically indexed)
    float pes[16], pdt[16], pss[16], ptt[16], psl[16];
#pragma unroll
    for (int i = 0; i < 16; ++i) {
        pes[i] = 0.f; pdt[i] = 0.f; pss[i] = 0.f; ptt[i] = 0.f; psl[i] = 0.f;
    }

    // A register double-buffer (int4 pairs; i32x8 assembled at use site so
    // the compiler's waitcnt lands next-iteration, not at issue).
    int4 aS0_a, aS1_a, aT0_a, aT1_a;      // parity 0 (even kt)
    int4 aS0_b, aS1_b, aT0_b, aT1_b;      // parity 1 (odd kt)

#define ALOAD(KTN, S0, S1, T0, T1)                                            \
    {                                                                         \
        const unsigned char* pa = aSrcS + (size_t)(KTN) * BLOBM;              \
        const unsigned char* pt = aSrcT + (size_t)(KTN) * BLOBM;              \
        S0 = *reinterpret_cast<const int4*>(pa);                              \
        S1 = *reinterpret_cast<const int4*>(pa + 1024);                       \
        T0 = *reinterpret_cast<const int4*>(pt);                              \
        T1 = *reinterpret_cast<const int4*>(pt + 1024);                       \
    }

#define BSTAGE(BIDX, SL)                                                      \
    {                                                                         \
        const int off16 = tid * 16;                                           \
        gl_lds16(bSrcS + (size_t)(BIDX) * BLOBM + off16, &smB[SL][0][off16]); \
        gl_lds16(bSrcT + (size_t)(BIDX) * BLOBM + off16, &smB[SL][1][off16]); \
    }

    // prologue: loads for step 0
    ALOAD(0, aS0_a, aS1_a, aT0_a, aT1_a);
    BSTAGE(0, 0);

    int bslot = 0;                        // slot of the step being computed
    for (int g = 0; g < VBG; ++g) {
        const int n0 = (vbg * VBG + g) * BN;
        f32x16 acc_s0 = {}, acc_s1 = {}, acc_t0 = {}, acc_t1 = {};

#pragma unroll
        for (int kt = 0; kt < NKTM; ++kt) {
            const int s = g * NKTM + kt;
            int nslot = bslot + 1; if (nslot == 3) nslot = 0;
            if (s + 1 < NSTEP) {
                if ((kt & 1) == 0) { ALOAD((kt + 1) & 7, aS0_b, aS1_b, aT0_b, aT1_b); }
                else               { ALOAD((kt + 1) & 7, aS0_a, aS1_a, aT0_a, aT1_a); }
                BSTAGE(s + 1, nslot);
                asm volatile("s_waitcnt vmcnt(6)" ::: "memory");
            } else {
                asm volatile("s_waitcnt vmcnt(0)" ::: "memory");
            }
            __builtin_amdgcn_sched_barrier(0);
            __builtin_amdgcn_s_barrier();
            {
                const unsigned char* bbS = &smB[bslot][0][0];
                const unsigned char* bbT = &smB[bslot][1][0];
                i32x8 fa, fb0, fb1;
                if ((kt & 1) == 0) fa = mk8(aS0_a, aS1_a);
                else               fa = mk8(aS0_b, aS1_b);
                fb0 = mk8(*reinterpret_cast<const int4*>(bbS + bo0),
                          *reinterpret_cast<const int4*>(bbS + bo0 + 1024));
                fb1 = mk8(*reinterpret_cast<const int4*>(bbS + bo1),
                          *reinterpret_cast<const int4*>(bbS + bo1 + 1024));
                acc_s0 = __builtin_amdgcn_mfma_scale_f32_32x32x64_f8f6f4(
                    fa, fb0, acc_s0, 0, 0, 0, 127, 0, 127);
                acc_s1 = __builtin_amdgcn_mfma_scale_f32_32x32x64_f8f6f4(
                    fa, fb1, acc_s1, 0, 0, 0, 127, 0, 127);
                if ((kt & 1) == 0) fa = mk8(aT0_a, aT1_a);
                else               fa = mk8(aT0_b, aT1_b);
                fb0 = mk8(*reinterpret_cast<const int4*>(bbT + bo0),
                          *reinterpret_cast<const int4*>(bbT + bo0 + 1024));
                fb1 = mk8(*reinterpret_cast<const int4*>(bbT + bo1),
                          *reinterpret_cast<const int4*>(bbT + bo1 + 1024));
                acc_t0 = __builtin_amdgcn_mfma_scale_f32_32x32x64_f8f6f4(
                    fa, fb0, acc_t0, 0, 0, 0, 127, 0, 127);
                acc_t1 = __builtin_amdgcn_mfma_scale_f32_32x32x64_f8f6f4(
                    fa, fb1, acc_t1, 0, 0, 0, 127, 0, 127);
            }
            bslot = nslot;
        }

        // accumulate into register partials (labels read from LDS)
        // C/D (32x32): col = lane&31, row = (reg&3)+8*(reg>>2)+4*(lane>>5)
#pragma unroll
        for (int rg = 0; rg < 16; ++rg) {
            const float s0 = acc_s0[rg], s1 = acc_s1[rg];
            const float t0 = acc_t0[rg], t1 = acc_t1[rg];
            pes[rg] += __expf(s0) + __expf(s1);
            pdt[rg] += s0 * t0 + s1 * t1;
            pss[rg] += s0 * s0 + s1 * s1;
            ptt[rg] += t0 * t0 + t1 * t1;
            const int lab = lbl[wm + (rg & 3) + 8 * (rg >> 2) + 4 * khalf];
            if (n0 + wn + lrow == lab)      psl[rg] += s0;
            if (n0 + wn + 32 + lrow == lab) psl[rg] += s1;
        }
    }

#undef ALOAD
#undef BSTAGE

    // one shuffle-reduce + one non-atomic write per rg for the whole strip
    const int slot = vbg * 2 + (wave & 1);
#pragma unroll
    for (int rg = 0; rg < 16; ++rg) {
        float es = pes[rg], dt = pdt[rg], ss = pss[rg], tt = ptt[rg], sl = psl[rg];
#pragma unroll
        for (int m = 1; m < 32; m <<= 1) {
            es += __shfl_xor(es, m, 64);
            dt += __shfl_xor(dt, m, 64);
            ss += __shfl_xor(ss, m, 64);
            tt += __shfl_xor(tt, m, 64);
            sl += __shfl_xor(sl, m, 64);
        }
        if (lrow == 0) {
            const int row = row0 + wm + (rg & 3) + 8 * (rg >> 2) + 4 * khalf;
            partials[(size_t)(0 * NSLOT + slot) * BTOK + row] = es;
            partials[(size_t)(1 * NSLOT + slot) * BTOK + row] = dt;
            partials[(size_t)(2 * NSLOT + slot) * BTOK + row] = ss;
            partials[(size_t)(3 * NSLOT + slot) * BTOK + row] = tt;
            partials[(size_t)(4 * NSLOT + slot) * BTOK + row] = sl;
        }
    }
}

// ---------------------------------------------------------------------------
// finalize stage 1: 32 blocks x 64 rows; reduce 100 slots (coalesced).
// ---------------------------------------------------------------------------
__global__ __launch_bounds__(256) void finalize_s1(
    const float* __restrict__ partials, const int* __restrict__ labels,
    float* __restrict__ blocksums)
{
    __shared__ float fsum[4][64][5];
    const int t = threadIdx.x, b = blockIdx.x;
    const int rl = t & 63, w = t >> 6;
    const int row = b * 64 + rl;
    float a0 = 0.f, a1 = 0.f, a2 = 0.f, a3 = 0.f, a4 = 0.f;
    for (int slot = w; slot < NSLOT; slot += 4) {
        const size_t base = (size_t)slot * BTOK + row;
        a0 += partials[(size_t)0 * NSLOT * BTOK + base];
        a1 += partials[(size_t)1 * NSLOT * BTOK + base];
        a2 += partials[(size_t)2 * NSLOT * BTOK + base];
        a3 += partials[(size_t)3 * NSLOT * BTOK + base];
        a4 += partials[(size_t)4 * NSLOT * BTOK + base];
    }
    fsum[w][rl][0] = a0; fsum[w][rl][1] = a1; fsum[w][rl][2] = a2;
    fsum[w][rl][3] = a3; fsum[w][rl][4] = a4;
    __syncthreads();
    if (t < 64) {
        const float es = fsum[0][t][0] + fsum[1][t][0] + fsum[2][t][0] + fsum[3][t][0];
        const float dt = fsum[0][t][1] + fsum[1][t][1] + fsum[2][t][1] + fsum[3][t][1];
        const float ss = fsum[0][t][2] + fsum[1][t][2] + fsum[2][t][2] + fsum[3][t][2];
        const float tt = fsum[0][t][3] + fsum[1][t][3] + fsum[2][t][3] + fsum[3][t][3];
        const float sl = fsum[0][t][4] + fsum[1][t][4] + fsum[2][t][4] + fsum[3][t][4];
        float hard = 0.f, soft;
        if (labels[row] != -100) hard = logf(es) - sl;
        const float ns = fmaxf(sqrtf(ss), 1e-12f);
        const float nt = fmaxf(sqrtf(tt), 1e-12f);
        soft = 1.f - dt / (ns * nt);
#pragma unroll
        for (int m = 1; m < 64; m <<= 1) {
            hard += __shfl_xor(hard, m, 64);
            soft += __shfl_xor(soft, m, 64);
        }
        if (t == 0) {
            blocksums[b * 2 + 0] = hard;
            blocksums[b * 2 + 1] = soft;
        }
    }
}

__global__ void finalize_s2(const float* __restrict__ blocksums,
                            float* __restrict__ out)
{
    const int t = threadIdx.x;   // 64
    float hard = (t < 32) ? blocksums[t * 2 + 0] : 0.f;
    float soft = (t < 32) ? blocksums[t * 2 + 1] : 0.f;
#pragma unroll
    for (int m = 1; m < 64; m <<= 1) {
        hard += __shfl_xor(hard, m, 64);
        soft += __shfl_xor(soft, m, 64);
    }
    if (t == 0)
        out[0] = 0.5f * (hard / (float)BTOK) + 0.25f * (soft / (float)BTOK);
}

// ---------------------------------------------------------------------------
// Fallback (ws too small): R2's validated bf16 fused-conversion kernel.
// ---------------------------------------------------------------------------
#define BKF 32
#define NKTF (HDIM / BKF)
#define TILE_EF (BM * BKF)

__device__ __forceinline__ int swz_e32(int r, int c) {
    return (r * BKF + c) ^ ((r & 7) << 3);
}

__global__ __launch_bounds__(256, 2) void fused_fwd_fb(
    const float* __restrict__ s_in, const float* __restrict__ s_w,
    const float* __restrict__ t_in, const float* __restrict__ t_w,
    const int* __restrict__ labels, float* __restrict__ rowacc)
{
    __shared__ unsigned short smem[2][4][TILE_EF];
    __shared__ int lbl[BM];
    const int tid = threadIdx.x;
    const int orig = blockIdx.x;
    const int swz  = (orig & 7) * (NBLK / 8) + (orig >> 3);
    const int vb = swz >> 4, rb = swz & 15;
    const int n0 = vb * BN, row0 = rb * BM;
    if (tid < BM) lbl[tid] = labels[row0 + tid];
    const int rr = tid >> 3, c8 = tid & 7;
    const float* srcp[4];
    srcp[0] = s_in + (size_t)(row0 + rr) * HDIM + c8 * 4;
    srcp[1] = s_w  + (size_t)(n0   + rr) * HDIM + c8 * 4;
    srcp[2] = t_in + (size_t)(row0 + rr) * HDIM + c8 * 4;
    srcp[3] = t_w  + (size_t)(n0   + rr) * HDIM + c8 * 4;
    f32x4 acc_s[4][4] = {}, acc_t[4][4] = {};
    const int lane = tid & 63, wave = tid >> 6;
    const int wm = (wave >> 1) * 64, wn = (wave & 1) * 64;
    const int lr = lane & 15, lg = lane >> 4;
    const int ec = lg * 8;
    float4 rg[4][4];

#define LOADS_FB(KT)                                                          \
    { const int k0 = (KT) * BKF;                                              \
      _Pragma("unroll") for (int t = 0; t < 4; ++t)                           \
      _Pragma("unroll") for (int it = 0; it < 4; ++it)                        \
          rg[t][it] = *reinterpret_cast<const float4*>(srcp[t] + (size_t)it * 32 * HDIM + k0); }
#define CVT_WRITE_FB(B)                                                       \
    { _Pragma("unroll") for (int t = 0; t < 4; ++t)                           \
      _Pragma("unroll") for (int it = 0; it < 4; ++it) {                      \
          const int r = rr + it * 32;                                         \
          ushort4 h;                                                          \
          h.x = f2b(rg[t][it].x); h.y = f2b(rg[t][it].y);                     \
          h.z = f2b(rg[t][it].z); h.w = f2b(rg[t][it].w);                     \
          *reinterpret_cast<ushort4*>(&smem[B][t][swz_e32(r, c8 * 4)]) = h; } }
#define COMPUTE_FB(B)                                                         \
    { const unsigned short* As = smem[B][0]; const unsigned short* Bs = smem[B][1]; \
      const unsigned short* At = smem[B][2]; const unsigned short* Bt = smem[B][3]; \
      bf16x8 af[4], bfr[4];                                                   \
      _Pragma("unroll") for (int mi = 0; mi < 4; ++mi)                        \
          af[mi] = *reinterpret_cast<const bf16x8*>(As + swz_e32(wm + mi * 16 + lr, ec)); \
      _Pragma("unroll") for (int ni = 0; ni < 4; ++ni)                        \
          bfr[ni] = *reinterpret_cast<const bf16x8*>(Bs + swz_e32(wn + ni * 16 + lr, ec)); \
      _Pragma("unroll") for (int mi = 0; mi < 4; ++mi)                        \
      _Pragma("unroll") for (int ni = 0; ni < 4; ++ni)                        \
          acc_s[mi][ni] = __builtin_amdgcn_mfma_f32_16x16x32_bf16(af[mi], bfr[ni], acc_s[mi][ni], 0, 0, 0); \
      _Pragma("unroll") for (int mi = 0; mi < 4; ++mi)                        \
          af[mi] = *reinterpret_cast<const bf16x8*>(At + swz_e32(wm + mi * 16 + lr, ec)); \
      _Pragma("unroll") for (int ni = 0; ni < 4; ++ni)                        \
          bfr[ni] = *reinterpret_cast<const bf16x8*>(Bt + swz_e32(wn + ni * 16 + lr, ec)); \
      _Pragma("unroll") for (int mi = 0; mi < 4; ++mi)                        \
      _Pragma("unroll") for (int ni = 0; ni < 4; ++ni)                        \
          acc_t[mi][ni] = __builtin_amdgcn_mfma_f32_16x16x32_bf16(af[mi], bfr[ni], acc_t[mi][ni], 0, 0, 0); }

    LOADS_FB(0); CVT_WRITE_FB(0); __syncthreads();
    int cur = 0;
#pragma unroll 2
    for (int kt = 0; kt < NKTF; ++kt) {
        if (kt + 1 < NKTF) LOADS_FB(kt + 1);
        COMPUTE_FB(cur);
        if (kt + 1 < NKTF) CVT_WRITE_FB(cur ^ 1);
        __syncthreads();
        cur ^= 1;
    }
#undef LOADS_FB
#undef CVT_WRITE_FB
#undef COMPUTE_FB
#pragma unroll
    for (int mi = 0; mi < 4; ++mi) {
#pragma unroll
        for (int rg_ = 0; rg_ < 4; ++rg_) {
            const int rloc = wm + mi * 16 + lg * 4 + rg_;
            const int lab = lbl[rloc];
            float es = 0.f, dt = 0.f, ss = 0.f, tt = 0.f, sl = 0.f;
#pragma unroll
            for (int ni = 0; ni < 4; ++ni) {
                const float s = acc_s[mi][ni][rg_];
                const float t = acc_t[mi][ni][rg_];
                es += __expf(s); dt += s * t; ss += s * s; tt += t * t;
                if (n0 + wn + ni * 16 + lr == lab) sl += s;
            }
#pragma unroll
            for (int m = 1; m < 16; m <<= 1) {
                es += __shfl_xor(es, m, 64); dt += __shfl_xor(dt, m, 64);
                ss += __shfl_xor(ss, m, 64); tt += __shfl_xor(tt, m, 64);
                sl += __shfl_xor(sl, m, 64);
            }
            if (lr == 0) {
                float* ra = rowacc + (size_t)(row0 + rloc) * 5;
                atomicAdd(ra + 0, es); atomicAdd(ra + 1, dt); atomicAdd(ra + 2, ss);
                atomicAdd(ra + 3, tt); atomicAdd(ra + 4, sl);
            }
        }
    }
}

__global__ __launch_bounds__(256) void finalize(const float* __restrict__ rowacc,
                                                const int* __restrict__ labels,
                                                float* __restrict__ out)
{
    const int tid = threadIdx.x;
    float hard = 0.f, soft = 0.f;
    for (int r = tid; r < BTOK; r += 256) {
        const float* ra = rowacc + (size_t)r * 5;
        const float es = ra[0], dt = ra[1], ss = ra[2], tt = ra[3], sl = ra[4];
        if (labels[r] != -100) hard += logf(es) - sl;
        const float ns = fmaxf(sqrtf(ss), 1e-12f);
        const float nt = fmaxf(sqrtf(tt), 1e-12f);
        soft += 1.f - dt / (ns * nt);
    }
#pragma unroll
    for (int m = 1; m < 64; m <<= 1) {
        hard += __shfl_xor(hard, m, 64);
        soft += __shfl_xor(soft, m, 64);
    }
    __shared__ float sh[2][4];
    const int w = tid >> 6;
    if ((tid & 63) == 0) { sh[0][w] = hard; sh[1][w] = soft; }
    __syncthreads();
    if (tid == 0) {
        const float h = sh[0][0] + sh[0][1] + sh[0][2] + sh[0][3];
        const float s = sh[1][0] + sh[1][1] + sh[1][2] + sh[1][3];
        out[0] = 0.5f * (h / (float)BTOK) + 0.5f * (0.5f * s / (float)BTOK);
    }
}

extern "C" void kernel_launch(void* const* d_in, const int* in_sizes, int n_in,
                              void* d_out, int out_size, void* d_ws, size_t ws_size,
                              hipStream_t stream)
{
    const float* s_in   = (const float*)d_in[0];
    const float* s_w    = (const float*)d_in[1];
    const float* t_in   = (const float*)d_in[2];
    const float* t_w    = (const float*)d_in[3];
    const int*   labels = (const int*)d_in[4];

    if (ws_size >= WS_NEED) {
        unsigned char* blob = (unsigned char*)d_ws + WS_BLOB_OFF;
        float* partials  = (float*)((char*)d_ws + PART_OFF);
        float* blocksums = (float*)d_ws;
        convert_pack_mx<<<2048, 256, 0, stream>>>(s_in, s_w, t_in, t_w, blob);
        fused_gemm_mx<<<NSTRIP, 512, 0, stream>>>(blob, labels, partials);
        finalize_s1<<<BTOK / 64, 256, 0, stream>>>(partials, labels, blocksums);
        finalize_s2<<<1, 64, 0, stream>>>(blocksums, (float*)d_out);
    } else {
        float* rowacc = (float*)d_ws;
        hipMemsetAsync(rowacc, 0, (size_t)BTOK * 5 * sizeof(float), stream);
        fused_fwd_fb<<<NBLK, 256, 0, stream>>>(s_in, s_w, t_in, t_w, labels, rowacc);
        finalize<<<1, 256, 0, stream>>>(rowacc, labels, (float*)d_out);
    }
}

// Round 15
// 192.356 us; speedup vs baseline: 4.8746x; 4.8746x over previous
//
#include <hip/hip_runtime.h>
#include <stdint.h>

#define BTOK 2048
#define HDIM 512
#define VOC  32000
#define BM 128
#define BN 128
#define BKM 64                   // K per step (MX 32x32x64)
#define NKTM (HDIM / BKM)        // 8 K-steps per vocab block
#define BLOBM (BM * BKM)         // 8192 B per (panel, kt) blob (fp8)
#define NVB (VOC / BN)           // 250
#define NRB (BTOK / BM)          // 16
#define NBLK (NVB * NRB)         // 4000 (fallback grid)
#define VBG 5                    // vocab blocks per strip
#define NVBG (NVB / VBG)         // 50
#define NSTRIP (NVBG * NRB)      // 800 (% 8 == 0)
#define NSLOT (NVBG * 2)         // 100 partial slots

// ws layout:
//   [0, 256)        blocksums
//   [65536, ..)     fp8 blobs: s_in | t_in | s_w | t_w
//   [PART_OFF, ..)  partials[5][NSLOT][BTOK] f32
#define WS_BLOB_OFF 65536
#define INB_B ((size_t)BTOK * HDIM)
#define WB_B  ((size_t)VOC * HDIM)
#define BLOB_BYTES (2 * INB_B + 2 * WB_B)          // 34,865,152
#define PART_OFF (WS_BLOB_OFF + BLOB_BYTES)
#define PART_BYTES ((size_t)5 * NSLOT * BTOK * 4)  // 4,096,000
#define WS_NEED (PART_OFF + PART_BYTES)            // ~39 MB

typedef __attribute__((ext_vector_type(8)))  short bf16x8;
typedef __attribute__((ext_vector_type(4)))  float f32x4;
typedef __attribute__((ext_vector_type(16))) float f32x16;
typedef __attribute__((ext_vector_type(8)))  int   i32x8;

__device__ __forceinline__ unsigned short f2b(float f) {
    union { float f; uint32_t u; } x; x.f = f;
    uint32_t u = x.u;
    u += 0x7fffu + ((u >> 16) & 1u);   // RNE (fallback path)
    return (unsigned short)(u >> 16);
}

// ---------------------------------------------------------------------------
// Pass 1: f32 -> fp8 e4m3 blobs. R15 piece-interleaved panel layout (from
// R14, the only validated-safe piece of it): byte (r, c) of a 128x64 panel:
//   e = (r>>5)*2048 + ((c&31)>>4)*1024 + ((c>>5)*32 + (r&31))*16 + (c&15)
// Lane l's 32B MFMA operand (row base+(l&31), khalf=l>>5) = two 16B pieces
// at opBase + l*16 and opBase + 1024 + l*16 -> consecutive lanes at 16B
// stride = the conflict-free ds_read pattern (R3 measured 0 conflicts at
// this stride; R12/R13's 32B lane stride = structural 4-way = the constant
// 1.229e7 counter).
// ---------------------------------------------------------------------------
__global__ __launch_bounds__(256) void convert_pack_mx(
    const float* __restrict__ s_in, const float* __restrict__ s_w,
    const float* __restrict__ t_in, const float* __restrict__ t_w,
    unsigned char* __restrict__ blob)
{
    unsigned char* sinb = blob;
    unsigned char* tinb = blob + INB_B;
    unsigned char* swb  = blob + 2 * INB_B;
    unsigned char* twb  = blob + 2 * INB_B + WB_B;
    const int total8 = (2 * BTOK + 2 * VOC) * (HDIM / 8);
    for (int f = blockIdx.x * 256 + threadIdx.x; f < total8; f += gridDim.x * 256) {
        const int row = f >> 6;
        const int c8i = f & 63;
        const float* src; unsigned char* dstb; int lrow;
        if (row < BTOK)                { src = s_in; dstb = sinb; lrow = row; }
        else if (row < BTOK + VOC)     { src = s_w;  dstb = swb;  lrow = row - BTOK; }
        else if (row < 2*BTOK + VOC)   { src = t_in; dstb = tinb; lrow = row - (BTOK + VOC); }
        else                           { src = t_w;  dstb = twb;  lrow = row - (2*BTOK + VOC); }
        const float* sp = src + (size_t)lrow * HDIM + c8i * 8;
        const float4 v0 = *reinterpret_cast<const float4*>(sp);
        const float4 v1 = *reinterpret_cast<const float4*>(sp + 4);
        const int p = lrow >> 7, r = lrow & 127;
        const int ccf = c8i * 8, kt = ccf >> 6, cc = ccf & 63;
        const int e = ((r >> 5) << 11) + (((cc & 31) >> 4) << 10)
                    + ((((cc >> 5) << 5) + (r & 31)) << 4) + (cc & 15);
        uint32_t w0 = 0, w1 = 0;
        w0 = __builtin_amdgcn_cvt_pk_fp8_f32(v0.x, v0.y, w0, false);
        w0 = __builtin_amdgcn_cvt_pk_fp8_f32(v0.z, v0.w, w0, true);
        w1 = __builtin_amdgcn_cvt_pk_fp8_f32(v1.x, v1.y, w1, false);
        w1 = __builtin_amdgcn_cvt_pk_fp8_f32(v1.z, v1.w, w1, true);
        uint2 pk; pk.x = w0; pk.y = w1;
        *reinterpret_cast<uint2*>(dstb + (size_t)(p * NKTM + kt) * BLOBM + e) = pk;
    }
}

__device__ __forceinline__ void gl_lds16(const unsigned char* g, unsigned char* l) {
    __builtin_amdgcn_global_load_lds(
        (__attribute__((address_space(1))) const void*)g,
        (__attribute__((address_space(3))) void*)l, 16, 0, 0);
}

// Read one 32B MFMA operand: two 16B pieces at p and p+1024 (16B lane
// stride -> conflict-free).
__device__ __forceinline__ i32x8 ld32pc(const unsigned char* p) {
    const int4 lo = *reinterpret_cast<const int4*>(p);
    const int4 hi = *reinterpret_cast<const int4*>(p + 1024);
    i32x8 v;
    v[0] = lo.x; v[1] = lo.y; v[2] = lo.z; v[3] = lo.w;
    v[4] = hi.x; v[5] = hi.y; v[6] = hi.z; v[7] = hi.w;
    return v;
}

// Stage A(KA) and B(KB) panels into buffer BUF (linear copy; layout is
// pre-arranged in the blob). A indexed mod-8, B linear (KB=8 = next g).
#define STAGE_AB(KA, KB, BUF)                                                 \
    {                                                                         \
        const int off = tid * 16;                                             \
        gl_lds16(g0 + (size_t)(KA) * BLOBM + off, &smem[BUF][0][off]);        \
        gl_lds16(pb1 + (size_t)(KB) * BLOBM + off, &smem[BUF][1][off]);       \
        gl_lds16(g2 + (size_t)(KA) * BLOBM + off, &smem[BUF][2][off]);        \
        gl_lds16(pb3 + (size_t)(KB) * BLOBM + off, &smem[BUF][3][off]);       \
    }

// Per wave: 1 A-frag + 2 B-frags per matrix, 4 mfma_scale (scale=1.0: E8M0 127).
// All LDS reads at 16B lane stride (conflict-free, R15 layout).
#define COMPUTE_MX(B)                                                         \
    {                                                                         \
        i32x8 fa, fb0, fb1;                                                   \
        fa  = ld32pc(&smem[B][0][aOff]);                                      \
        fb0 = ld32pc(&smem[B][1][b0Off]);                                     \
        fb1 = ld32pc(&smem[B][1][b1Off]);                                     \
        acc_s0 = __builtin_amdgcn_mfma_scale_f32_32x32x64_f8f6f4(             \
            fa, fb0, acc_s0, 0, 0, 0, 127, 0, 127);                           \
        acc_s1 = __builtin_amdgcn_mfma_scale_f32_32x32x64_f8f6f4(             \
            fa, fb1, acc_s1, 0, 0, 0, 127, 0, 127);                           \
        fa  = ld32pc(&smem[B][2][aOff]);                                      \
        fb0 = ld32pc(&smem[B][3][b0Off]);                                     \
        fb1 = ld32pc(&smem[B][3][b1Off]);                                     \
        acc_t0 = __builtin_amdgcn_mfma_scale_f32_32x32x64_f8f6f4(             \
            fa, fb0, acc_t0, 0, 0, 0, 127, 0, 127);                           \
        acc_t1 = __builtin_amdgcn_mfma_scale_f32_32x32x64_f8f6f4(             \
            fa, fb1, acc_t1, 0, 0, 0, 127, 0, 127);                          \
    }

#define CORE(B, VM)                                                           \
    {                                                                         \
        asm volatile("s_waitcnt vmcnt(" #VM ")" ::: "memory");                \
        __builtin_amdgcn_sched_barrier(0);                                    \
        __builtin_amdgcn_s_barrier();                                         \
        COMPUTE_MX(B);                                                        \
        __builtin_amdgcn_s_barrier();                                         \
    }

// ---------------------------------------------------------------------------
// Strip GEMM (MX fp8 32x32x64, 8 waves, VBG=5). EXACT R12/R13 skeleton (the
// proven no-spill envelope: runtime g-loop, 8-step unrolled body, gl_lds
// dbuf, 64 acc + 80 partials live) + R15 conflict-free piece layout. R14's
// A-in-registers/ring-3 restructure spilled (1.75 GB scratch) - reverted.
// ---------------------------------------------------------------------------
__global__ __launch_bounds__(512, 2) void fused_gemm_mx(
    const unsigned char* __restrict__ blob,
    const int* __restrict__ labels, float* __restrict__ partials)
{
    __shared__ __align__(16) unsigned char smem[2][4][BLOBM];   // 64 KB
    __shared__ int lbl[BM];
    const unsigned char* sinb = blob;
    const unsigned char* tinb = blob + INB_B;
    const unsigned char* swb  = blob + 2 * INB_B;
    const unsigned char* twb  = blob + 2 * INB_B + WB_B;

    const int tid = threadIdx.x;
    const int orig = blockIdx.x;
    const int swzb = (orig & 7) * (NSTRIP / 8) + (orig >> 3);   // XCD-bijective
    const int vbg = swzb >> 4, rb = swzb & 15;
    const int row0 = rb * BM;
    if (tid < BM) lbl[tid] = labels[row0 + tid];
    __syncthreads();

    const int lane = tid & 63, wave = tid >> 6;
    const int wm = (wave >> 1) * 32;      // 4 M-strips of 32
    const int wn = (wave & 1) * 64;       // 2 N-strips of 64
    const int lrow = lane & 31, khalf = lane >> 5;

    // R15 piece-layout fragment offsets: strip*2048 + lane*16 (piece1 +1024)
    const int aOff  = ((wm >> 5) << 11) + lane * 16;
    const int b0Off = ((wn >> 5) << 11) + lane * 16;
    const int b1Off = b0Off + 2048;

    const unsigned char* g0 = sinb + (size_t)(rb * NKTM) * BLOBM;
    const unsigned char* g2 = tinb + (size_t)(rb * NKTM) * BLOBM;
    const unsigned char* pb1 = swb + (size_t)(vbg * VBG * NKTM) * BLOBM;
    const unsigned char* pb3 = twb + (size_t)(vbg * VBG * NKTM) * BLOBM;

    // labels for this thread's 16 output rows, hoisted to registers
    int labr[16];
#pragma unroll
    for (int rg = 0; rg < 16; ++rg)
        labr[rg] = lbl[wm + (rg & 3) + 8 * (rg >> 2) + 4 * khalf];

    // strip-accumulated loss partials (statically indexed)
    float pes[16], pdt[16], pss[16], ptt[16], psl[16];
#pragma unroll
    for (int i = 0; i < 16; ++i) {
        pes[i] = 0.f; pdt[i] = 0.f; pss[i] = 0.f; ptt[i] = 0.f; psl[i] = 0.f;
    }

    STAGE_AB(0, 0, 0);                    // prologue: 4 loads in flight

    for (int g = 0; g < VBG; ++g) {
        const int n0 = (vbg * VBG + g) * BN;
        f32x16 acc_s0 = {}, acc_s1 = {}, acc_t0 = {}, acc_t1 = {};

        if (g < VBG - 1) {
#pragma unroll
            for (int kt = 0; kt < NKTM - 1; ++kt) {
                STAGE_AB(kt + 1, kt + 1, (kt + 1) & 1);
                CORE(kt & 1, 4);
            }
            STAGE_AB(0, NKTM, 0);         // next g: A(0), B(next block's 0)
            CORE(1, 4);
        } else {
#pragma unroll
            for (int kt = 0; kt < NKTM - 1; ++kt) {
                STAGE_AB(kt + 1, kt + 1, (kt + 1) & 1);
                CORE(kt & 1, 4);
            }
            CORE(1, 0);                   // only full drain in the kernel
        }
        pb1 += (size_t)NKTM * BLOBM;
        pb3 += (size_t)NKTM * BLOBM;

        // accumulate into register partials
        // C/D (32x32): col = lane&31, row = (reg&3)+8*(reg>>2)+4*(lane>>5)
#pragma unroll
        for (int rg = 0; rg < 16; ++rg) {
            const float s0 = acc_s0[rg], s1 = acc_s1[rg];
            const float t0 = acc_t0[rg], t1 = acc_t1[rg];
            pes[rg] += __expf(s0) + __expf(s1);
            pdt[rg] += s0 * t0 + s1 * t1;
            pss[rg] += s0 * s0 + s1 * s1;
            ptt[rg] += t0 * t0 + t1 * t1;
            const int lab = labr[rg];
            if (n0 + wn + lrow == lab)      psl[rg] += s0;
            if (n0 + wn + 32 + lrow == lab) psl[rg] += s1;
        }
    }

    // one shuffle-reduce + one non-atomic write per rg for the whole strip
    const int slot = vbg * 2 + (wave & 1);
#pragma unroll
    for (int rg = 0; rg < 16; ++rg) {
        float es = pes[rg], dt = pdt[rg], ss = pss[rg], tt = ptt[rg], sl = psl[rg];
#pragma unroll
        for (int m = 1; m < 32; m <<= 1) {
            es += __shfl_xor(es, m, 64);
            dt += __shfl_xor(dt, m, 64);
            ss += __shfl_xor(ss, m, 64);
            tt += __shfl_xor(tt, m, 64);
            sl += __shfl_xor(sl, m, 64);
        }
        if (lrow == 0) {
            const int row = row0 + wm + (rg & 3) + 8 * (rg >> 2) + 4 * khalf;
            partials[(size_t)(0 * NSLOT + slot) * BTOK + row] = es;
            partials[(size_t)(1 * NSLOT + slot) * BTOK + row] = dt;
            partials[(size_t)(2 * NSLOT + slot) * BTOK + row] = ss;
            partials[(size_t)(3 * NSLOT + slot) * BTOK + row] = tt;
            partials[(size_t)(4 * NSLOT + slot) * BTOK + row] = sl;
        }
    }
}

// ---------------------------------------------------------------------------
// finalize stage 1: 32 blocks x 64 rows; reduce 100 slots (coalesced).
// ---------------------------------------------------------------------------
__global__ __launch_bounds__(256) void finalize_s1(
    const float* __restrict__ partials, const int* __restrict__ labels,
    float* __restrict__ blocksums)
{
    __shared__ float fsum[4][64][5];
    const int t = threadIdx.x, b = blockIdx.x;
    const int rl = t & 63, w = t >> 6;
    const int row = b * 64 + rl;
    float a0 = 0.f, a1 = 0.f, a2 = 0.f, a3 = 0.f, a4 = 0.f;
    for (int slot = w; slot < NSLOT; slot += 4) {
        const size_t base = (size_t)slot * BTOK + row;
        a0 += partials[(size_t)0 * NSLOT * BTOK + base];
        a1 += partials[(size_t)1 * NSLOT * BTOK + base];
        a2 += partials[(size_t)2 * NSLOT * BTOK + base];
        a3 += partials[(size_t)3 * NSLOT * BTOK + base];
        a4 += partials[(size_t)4 * NSLOT * BTOK + base];
    }
    fsum[w][rl][0] = a0; fsum[w][rl][1] = a1; fsum[w][rl][2] = a2;
    fsum[w][rl][3] = a3; fsum[w][rl][4] = a4;
    __syncthreads();
    if (t < 64) {
        const float es = fsum[0][t][0] + fsum[1][t][0] + fsum[2][t][0] + fsum[3][t][0];
        const float dt = fsum[0][t][1] + fsum[1][t][1] + fsum[2][t][1] + fsum[3][t][1];
        const float ss = fsum[0][t][2] + fsum[1][t][2] + fsum[2][t][2] + fsum[3][t][2];
        const float tt = fsum[0][t][3] + fsum[1][t][3] + fsum[2][t][3] + fsum[3][t][3];
        const float sl = fsum[0][t][4] + fsum[1][t][4] + fsum[2][t][4] + fsum[3][t][4];
        float hard = 0.f, soft;
        if (labels[row] != -100) hard = logf(es) - sl;
        const float ns = fmaxf(sqrtf(ss), 1e-12f);
        const float nt = fmaxf(sqrtf(tt), 1e-12f);
        soft = 1.f - dt / (ns * nt);
#pragma unroll
        for (int m = 1; m < 64; m <<= 1) {
            hard += __shfl_xor(hard, m, 64);
            soft += __shfl_xor(soft, m, 64);
        }
        if (t == 0) {
            blocksums[b * 2 + 0] = hard;
            blocksums[b * 2 + 1] = soft;
        }
    }
}

__global__ void finalize_s2(const float* __restrict__ blocksums,
                            float* __restrict__ out)
{
    const int t = threadIdx.x;   // 64
    float hard = (t < 32) ? blocksums[t * 2 + 0] : 0.f;
    float soft = (t < 32) ? blocksums[t * 2 + 1] : 0.f;
#pragma unroll
    for (int m = 1; m < 64; m <<= 1) {
        hard += __shfl_xor(hard, m, 64);
        soft += __shfl_xor(soft, m, 64);
    }
    if (t == 0)
        out[0] = 0.5f * (hard / (float)BTOK) + 0.25f * (soft / (float)BTOK);
}

// ---------------------------------------------------------------------------
// Fallback (ws too small): R2's validated bf16 fused-conversion kernel.
// ---------------------------------------------------------------------------
#define BKF 32
#define NKTF (HDIM / BKF)
#define TILE_EF (BM * BKF)

__device__ __forceinline__ int swz_e32(int r, int c) {
    return (r * BKF + c) ^ ((r & 7) << 3);
}

__global__ __launch_bounds__(256, 2) void fused_fwd_fb(
    const float* __restrict__ s_in, const float* __restrict__ s_w,
    const float* __restrict__ t_in, const float* __restrict__ t_w,
    const int* __restrict__ labels, float* __restrict__ rowacc)
{
    __shared__ unsigned short smem[2][4][TILE_EF];
    __shared__ int lbl[BM];
    const int tid = threadIdx.x;
    const int orig = blockIdx.x;
    const int swz  = (orig & 7) * (NBLK / 8) + (orig >> 3);
    const int vb = swz >> 4, rb = swz & 15;
    const int n0 = vb * BN, row0 = rb * BM;
    if (tid < BM) lbl[tid] = labels[row0 + tid];
    const int rr = tid >> 3, c8 = tid & 7;
    const float* srcp[4];
    srcp[0] = s_in + (size_t)(row0 + rr) * HDIM + c8 * 4;
    srcp[1] = s_w  + (size_t)(n0   + rr) * HDIM + c8 * 4;
    srcp[2] = t_in + (size_t)(row0 + rr) * HDIM + c8 * 4;
    srcp[3] = t_w  + (size_t)(n0   + rr) * HDIM + c8 * 4;
    f32x4 acc_s[4][4] = {}, acc_t[4][4] = {};
    const int lane = tid & 63, wave = tid >> 6;
    const int wm = (wave >> 1) * 64, wn = (wave & 1) * 64;
    const int lr = lane & 15, lg = lane >> 4;
    const int ec = lg * 8;
    float4 rg[4][4];

#define LOADS_FB(KT)                                                          \
    { const int k0 = (KT) * BKF;                                              \
      _Pragma("unroll") for (int t = 0; t < 4; ++t)                           \
      _Pragma("unroll") for (int it = 0; it < 4; ++it)                        \
          rg[t][it] = *reinterpret_cast<const float4*>(srcp[t] + (size_t)it * 32 * HDIM + k0); }
#define CVT_WRITE_FB(B)                                                       \
    { _Pragma("unroll") for (int t = 0; t < 4; ++t)                           \
      _Pragma("unroll") for (int it = 0; it < 4; ++it) {                      \
          const int r = rr + it * 32;                                         \
          ushort4 h;                                                          \
          h.x = f2b(rg[t][it].x); h.y = f2b(rg[t][it].y);                     \
          h.z = f2b(rg[t][it].z); h.w = f2b(rg[t][it].w);                     \
          *reinterpret_cast<ushort4*>(&smem[B][t][swz_e32(r, c8 * 4)]) = h; } }
#define COMPUTE_FB(B)                                                         \
    { const unsigned short* As = smem[B][0]; const unsigned short* Bs = smem[B][1]; \
      const unsigned short* At = smem[B][2]; const unsigned short* Bt = smem[B][3]; \
      bf16x8 af[4], bfr[4];                                                   \
      _Pragma("unroll") for (int mi = 0; mi < 4; ++mi)                        \
          af[mi] = *reinterpret_cast<const bf16x8*>(As + swz_e32(wm + mi * 16 + lr, ec)); \
      _Pragma("unroll") for (int ni = 0; ni < 4; ++ni)                        \
          bfr[ni] = *reinterpret_cast<const bf16x8*>(Bs + swz_e32(wn + ni * 16 + lr, ec)); \
      _Pragma("unroll") for (int mi = 0; mi < 4; ++mi)                        \
      _Pragma("unroll") for (int ni = 0; ni < 4; ++ni)                        \
          acc_s[mi][ni] = __builtin_amdgcn_mfma_f32_16x16x32_bf16(af[mi], bfr[ni], acc_s[mi][ni], 0, 0, 0); \
      _Pragma("unroll") for (int mi = 0; mi < 4; ++mi)                        \
          af[mi] = *reinterpret_cast<const bf16x8*>(At + swz_e32(wm + mi * 16 + lr, ec)); \
      _Pragma("unroll") for (int ni = 0; ni < 4; ++ni)                        \
          bfr[ni] = *reinterpret_cast<const bf16x8*>(Bt + swz_e32(wn + ni * 16 + lr, ec)); \
      _Pragma("unroll") for (int mi = 0; mi < 4; ++mi)                        \
      _Pragma("unroll") for (int ni = 0; ni < 4; ++ni)                        \
          acc_t[mi][ni] = __builtin_amdgcn_mfma_f32_16x16x32_bf16(af[mi], bfr[ni], acc_t[mi][ni], 0, 0, 0); }

    LOADS_FB(0); CVT_WRITE_FB(0); __syncthreads();
    int cur = 0;
#pragma unroll 2
    for (int kt = 0; kt < NKTF; ++kt) {
        if (kt + 1 < NKTF) LOADS_FB(kt + 1);
        COMPUTE_FB(cur);
        if (kt + 1 < NKTF) CVT_WRITE_FB(cur ^ 1);
        __syncthreads();
        cur ^= 1;
    }
#undef LOADS_FB
#undef CVT_WRITE_FB
#undef COMPUTE_FB
#pragma unroll
    for (int mi = 0; mi < 4; ++mi) {
#pragma unroll
        for (int rg_ = 0; rg_ < 4; ++rg_) {
            const int rloc = wm + mi * 16 + lg * 4 + rg_;
            const int lab = lbl[rloc];
            float es = 0.f, dt = 0.f, ss = 0.f, tt = 0.f, sl = 0.f;
#pragma unroll
            for (int ni = 0; ni < 4; ++ni) {
                const float s = acc_s[mi][ni][rg_];
                const float t = acc_t[mi][ni][rg_];
                es += __expf(s); dt += s * t; ss += s * s; tt += t * t;
                if (n0 + wn + ni * 16 + lr == lab) sl += s;
            }
#pragma unroll
            for (int m = 1; m < 16; m <<= 1) {
                es += __shfl_xor(es, m, 64); dt += __shfl_xor(dt, m, 64);
                ss += __shfl_xor(ss, m, 64); tt += __shfl_xor(tt, m, 64);
                sl += __shfl_xor(sl, m, 64);
            }
            if (lr == 0) {
                float* ra = rowacc + (size_t)(row0 + rloc) * 5;
                atomicAdd(ra + 0, es); atomicAdd(ra + 1, dt); atomicAdd(ra + 2, ss);
                atomicAdd(ra + 3, tt); atomicAdd(ra + 4, sl);
            }
        }
    }
}

__global__ __launch_bounds__(256) void finalize(const float* __restrict__ rowacc,
                                                const int* __restrict__ labels,
                                                float* __restrict__ out)
{
    const int tid = threadIdx.x;
    float hard = 0.f, soft = 0.f;
    for (int r = tid; r < BTOK; r += 256) {
        const float* ra = rowacc + (size_t)r * 5;
        const float es = ra[0], dt = ra[1], ss = ra[2], tt = ra[3], sl = ra[4];
        if (labels[r] != -100) hard += logf(es) - sl;
        const float ns = fmaxf(sqrtf(ss), 1e-12f);
        const float nt = fmaxf(sqrtf(tt), 1e-12f);
        soft += 1.f - dt / (ns * nt);
    }
#pragma unroll
    for (int m = 1; m < 64; m <<= 1) {
        hard += __shfl_xor(hard, m, 64);
        soft += __shfl_xor(soft, m, 64);
    }
    __shared__ float sh[2][4];
    const int w = tid >> 6;
    if ((tid & 63) == 0) { sh[0][w] = hard; sh[1][w] = soft; }
    __syncthreads();
    if (tid == 0) {
        const float h = sh[0][0] + sh[0][1] + sh[0][2] + sh[0][3];
        const float s = sh[1][0] + sh[1][1] + sh[1][2] + sh[1][3];
        out[0] = 0.5f * (h / (float)BTOK) + 0.5f * (0.5f * s / (float)BTOK);
    }
}

extern "C" void kernel_launch(void* const* d_in, const int* in_sizes, int n_in,
                              void* d_out, int out_size, void* d_ws, size_t ws_size,
                              hipStream_t stream)
{
    const float* s_in   = (const float*)d_in[0];
    const float* s_w    = (const float*)d_in[1];
    const float* t_in   = (const float*)d_in[2];
    const float* t_w    = (const float*)d_in[3];
    const int*   labels = (const int*)d_in[4];

    if (ws_size >= WS_NEED) {
        unsigned char* blob = (unsigned char*)d_ws + WS_BLOB_OFF;
        float* partials  = (float*)((char*)d_ws + PART_OFF);
        float* blocksums = (float*)d_ws;
        convert_pack_mx<<<2048, 256, 0, stream>>>(s_in, s_w, t_in, t_w, blob);
        fused_gemm_mx<<<NSTRIP, 512, 0, stream>>>(blob, labels, partials);
        finalize_s1<<<BTOK / 64, 256, 0, stream>>>(partials, labels, blocksums);
        finalize_s2<<<1, 64, 0, stream>>>(blocksums, (float*)d_out);
    } else {
        float* rowacc = (float*)d_ws;
        hipMemsetAsync(rowacc, 0, (size_t)BTOK * 5 * sizeof(float), stream);
        fused_fwd_fb<<<NBLK, 256, 0, stream>>>(s_in, s_w, t_in, t_w, labels, rowacc);
        finalize<<<1, 256, 0, stream>>>(rowacc, labels, (float*)d_out);
    }
}